// Round 3
// baseline (125.443 us; speedup 1.0000x reference)
//
#include <hip/hip_runtime.h>
#include <math.h>

namespace {
constexpr int kB = 2;
constexpr int kL = 2048;
constexpr int kD = 1024;
constexpr int kN = 16;
constexpr int kChunk = 32;
constexpr int kNC = kL / kChunk;  // 64
constexpr int kPF = 8;            // x prefetch depth
}

// delta = softplus(exp(log_dt))  — NOTE the inner exp: reference does
//   dt = exp(log_dt); delta = softplus(dt)
__device__ __forceinline__ float s4_delta(float log_dt) {
  return log1pf(expf(expf(log_dt)));
}

// ---------------------------------------------------------------------------
// K1: per (b, chunk, d) thread — scan kChunk steps of g' = dA*g + x with g0=0,
// store the 16 complex end states. lane = d (coalesced x loads).
// 2048 blocks x 64 = 2 waves/SIMD.
// ---------------------------------------------------------------------------
__global__ __launch_bounds__(64) void s4_chunk_state(
    const float* __restrict__ X, const float* __restrict__ log_dt,
    const float* __restrict__ A_real_log, const float* __restrict__ A_imag,
    float* __restrict__ GE)
{
  const int lane = threadIdx.x;
  const int blk = blockIdx.x;
  const int dblk = blk & 15;              // D/64 = 16
  const int c = (blk >> 4) & (kNC - 1);   // NC = 64
  const int b = blk >> 10;
  const int d = dblk * 64 + lane;

  const float delta = s4_delta(log_dt[d]);

  float are[kN], aimv[kN];
  const float4* arl4 = reinterpret_cast<const float4*>(A_real_log + (size_t)d * kN);
  const float4* ai4  = reinterpret_cast<const float4*>(A_imag + (size_t)d * kN);
  #pragma unroll
  for (int q = 0; q < 4; ++q) {
    float4 a = arl4[q];
    float4 im = ai4[q];
    float v[4] = {a.x, a.y, a.z, a.w};
    float w[4] = {im.x, im.y, im.z, im.w};
    #pragma unroll
    for (int j = 0; j < 4; ++j) {
      const int n = q * 4 + j;
      float mag = expf(-delta * expf(v[j]));
      float ph = delta * w[j];
      are[n] = mag * cosf(ph);
      aimv[n] = mag * sinf(ph);
    }
  }

  float gre[kN], gim[kN];
  #pragma unroll
  for (int n = 0; n < kN; ++n) { gre[n] = 0.f; gim[n] = 0.f; }

  const float* xp = X + ((size_t)b * kL + (size_t)c * kChunk) * kD + d;

  float xbuf[kPF];
  #pragma unroll
  for (int i = 0; i < kPF; ++i) xbuf[i] = xp[(size_t)i * kD];

  #pragma unroll
  for (int t = 0; t < kChunk; ++t) {
    const float x = xbuf[t % kPF];
    if (t + kPF < kChunk) xbuf[t % kPF] = xp[(size_t)(t + kPF) * kD];
    #pragma unroll
    for (int n = 0; n < kN; ++n) {
      float tre = fmaf(are[n], gre[n], x);     // x is real: only re gets it
      float tim = are[n] * gim[n];
      float nre = fmaf(-aimv[n], gim[n], tre);
      float nim = fmaf(aimv[n], gre[n], tim);
      gre[n] = nre;
      gim[n] = nim;
    }
  }

  float* gp = GE + ((size_t)(b * kNC + c) * kN * 2) * kD + d;
  #pragma unroll
  for (int n = 0; n < kN; ++n) {
    gp[(size_t)(2 * n) * kD] = gre[n];
    gp[(size_t)(2 * n + 1) * kD] = gim[n];
  }
}

// ---------------------------------------------------------------------------
// K2: per (b, n, d) thread — sequential scan over the NC chunks:
//   carry[c] = s_c,  s_{c+1} = dA^kChunk * s_c + end[c],  s_0 = 0
// dA^kChunk computed directly as exp(kChunk*delta*A).
// ---------------------------------------------------------------------------
__global__ __launch_bounds__(256) void s4_carry(
    const float* __restrict__ GE, const float* __restrict__ log_dt,
    const float* __restrict__ A_real_log, const float* __restrict__ A_imag,
    float* __restrict__ CA)
{
  const int tid = blockIdx.x * 256 + threadIdx.x;  // 0 .. B*N*D-1
  const int d = tid & (kD - 1);
  const int bn = tid >> 10;
  const int n = bn & (kN - 1);
  const int b = bn >> 4;

  const float delta = s4_delta(log_dt[d]);
  const float arl = A_real_log[(size_t)d * kN + n];
  const float aim = A_imag[(size_t)d * kN + n];
  const float LT = delta * (float)kChunk;
  const float mag = expf(-LT * expf(arl));
  const float ph = LT * aim;
  const float aTre = mag * cosf(ph);
  const float aTim = mag * sinf(ph);

  float sre = 0.f, sim = 0.f;
  #pragma unroll 8
  for (int c = 0; c < kNC; ++c) {
    const size_t idx = ((size_t)((b * kNC + c) * kN + n) * 2) * kD + d;
    const float ere = GE[idx];
    const float eim = GE[idx + kD];
    CA[idx] = sre;
    CA[idx + kD] = sim;
    const float nre = fmaf(aTre, sre, fmaf(-aTim, sim, ere));
    const float nim = fmaf(aTre, sim, fmaf(aTim, sre, eim));
    sre = nre;
    sim = nim;
  }
}

// ---------------------------------------------------------------------------
// K3: per (b, chunk, d) thread — re-scan the chunk starting from the carry,
// emit y_t = x*D + sum_n 2*Re(C*dB * g) each step. Coalesced stores.
// ---------------------------------------------------------------------------
__global__ __launch_bounds__(64) void s4_chunk_out(
    const float* __restrict__ X, const float* __restrict__ log_dt,
    const float* __restrict__ A_real_log, const float* __restrict__ A_imag,
    const float* __restrict__ B_re, const float* __restrict__ B_im,
    const float* __restrict__ C_re, const float* __restrict__ C_im,
    const float* __restrict__ Dparam, const float* __restrict__ CA,
    float* __restrict__ Y)
{
  const int lane = threadIdx.x;
  const int blk = blockIdx.x;
  const int dblk = blk & 15;
  const int c = (blk >> 4) & (kNC - 1);
  const int b = blk >> 10;
  const int d = dblk * 64 + lane;

  const float delta = s4_delta(log_dt[d]);

  float are[kN], aimv[kN], cbre[kN], cbim[kN];
  {
    const float4* arl4 = reinterpret_cast<const float4*>(A_real_log + (size_t)d * kN);
    const float4* ai4  = reinterpret_cast<const float4*>(A_imag + (size_t)d * kN);
    const float4* br4  = reinterpret_cast<const float4*>(B_re + (size_t)d * kN);
    const float4* bi4  = reinterpret_cast<const float4*>(B_im + (size_t)d * kN);
    const float4* cr4  = reinterpret_cast<const float4*>(C_re + (size_t)d * kN);
    const float4* ci4  = reinterpret_cast<const float4*>(C_im + (size_t)d * kN);
    #pragma unroll
    for (int q = 0; q < 4; ++q) {
      float4 a = arl4[q];
      float4 im = ai4[q];
      float4 br = br4[q];
      float4 bi = bi4[q];
      float4 cr = cr4[q];
      float4 ci = ci4[q];
      float av[4] = {a.x, a.y, a.z, a.w};
      float iv[4] = {im.x, im.y, im.z, im.w};
      float brv[4] = {br.x, br.y, br.z, br.w};
      float biv[4] = {bi.x, bi.y, bi.z, bi.w};
      float crv[4] = {cr.x, cr.y, cr.z, cr.w};
      float civ[4] = {ci.x, ci.y, ci.z, ci.w};
      #pragma unroll
      for (int j = 0; j < 4; ++j) {
        const int n = q * 4 + j;
        float mag = expf(-delta * expf(av[j]));
        float ph = delta * iv[j];
        are[n] = mag * cosf(ph);
        aimv[n] = mag * sinf(ph);
        float dbre = delta * brv[j];
        float dbim = delta * biv[j];
        cbre[n] = 2.f * (crv[j] * dbre - civ[j] * dbim);   // 2*Re/Im of C*dB
        cbim[n] = 2.f * (crv[j] * dbim + civ[j] * dbre);
      }
    }
  }
  const float Dd = Dparam[d];

  // init g from carries
  float gre[kN], gim[kN];
  const float* cp = CA + ((size_t)(b * kNC + c) * kN * 2) * kD + d;
  #pragma unroll
  for (int n = 0; n < kN; ++n) {
    gre[n] = cp[(size_t)(2 * n) * kD];
    gim[n] = cp[(size_t)(2 * n + 1) * kD];
  }

  const size_t base = ((size_t)b * kL + (size_t)c * kChunk) * kD + d;
  const float* xp = X + base;
  float* yp = Y + base;

  float xbuf[kPF];
  #pragma unroll
  for (int i = 0; i < kPF; ++i) xbuf[i] = xp[(size_t)i * kD];

  #pragma unroll
  for (int t = 0; t < kChunk; ++t) {
    const float x = xbuf[t % kPF];
    if (t + kPF < kChunk) xbuf[t % kPF] = xp[(size_t)(t + kPF) * kD];
    float ya0 = x * Dd;
    float ya1 = 0.f, ya2 = 0.f, ya3 = 0.f;
    #pragma unroll
    for (int n = 0; n < kN; ++n) {
      float tre = fmaf(are[n], gre[n], x);
      float tim = are[n] * gim[n];
      float nre = fmaf(-aimv[n], gim[n], tre);
      float nim = fmaf(aimv[n], gre[n], tim);
      gre[n] = nre;
      gim[n] = nim;
      // y += 2*Re((C*dB) * g) — 4 independent accumulator chains
      if ((n & 3) == 0) { ya0 = fmaf(cbre[n], nre, ya0); ya0 = fmaf(-cbim[n], nim, ya0); }
      else if ((n & 3) == 1) { ya1 = fmaf(cbre[n], nre, ya1); ya1 = fmaf(-cbim[n], nim, ya1); }
      else if ((n & 3) == 2) { ya2 = fmaf(cbre[n], nre, ya2); ya2 = fmaf(-cbim[n], nim, ya2); }
      else { ya3 = fmaf(cbre[n], nre, ya3); ya3 = fmaf(-cbim[n], nim, ya3); }
    }
    yp[(size_t)t * kD] = (ya0 + ya1) + (ya2 + ya3);
  }
}

extern "C" void kernel_launch(void* const* d_in, const int* in_sizes, int n_in,
                              void* d_out, int out_size, void* d_ws, size_t ws_size,
                              hipStream_t stream) {
  const float* X          = (const float*)d_in[0];
  const float* log_dt     = (const float*)d_in[1];
  const float* A_real_log = (const float*)d_in[2];
  const float* A_imag     = (const float*)d_in[3];
  const float* B_re       = (const float*)d_in[4];
  const float* B_im       = (const float*)d_in[5];
  const float* C_re       = (const float*)d_in[6];
  const float* C_im       = (const float*)d_in[7];
  const float* Dparam     = (const float*)d_in[8];
  float* Y = (float*)d_out;

  // Chunk end-states (B*NC*N*2*D = 4.2M floats = 16.8 MB) live in d_out;
  // K3 never reads GE (only CA) and overwrites the region with y.
  float* GE = Y;
  // Carries (16.8 MB) in workspace.
  float* CA = (float*)d_ws;

  const int nblk = kB * kNC * (kD / 64);  // 2048
  s4_chunk_state<<<nblk, 64, 0, stream>>>(X, log_dt, A_real_log, A_imag, GE);
  s4_carry<<<(kB * kN * kD) / 256, 256, 0, stream>>>(GE, log_dt, A_real_log, A_imag, CA);
  s4_chunk_out<<<nblk, 64, 0, stream>>>(X, log_dt, A_real_log, A_imag,
                                        B_re, B_im, C_re, C_im, Dparam, CA, Y);
}

// Round 4
// 123.386 us; speedup vs baseline: 1.0167x; 1.0167x over previous
//
#include <hip/hip_runtime.h>
#include <math.h>

namespace {
constexpr int kB = 2;
constexpr int kL = 2048;
constexpr int kD = 1024;
constexpr int kN = 16;
constexpr int kChunk = 64;
constexpr int kNC = kL / kChunk;  // 32
constexpr int kPF = 8;            // x prefetch depth (divides kChunk)
}

// delta = softplus(exp(log_dt))  — NOTE the inner exp: reference does
//   dt = exp(log_dt); delta = softplus(dt)
__device__ __forceinline__ float s4_delta(float log_dt) {
  return log1pf(expf(expf(log_dt)));
}

// ---------------------------------------------------------------------------
// K1: per (b, chunk, d) thread — scan kChunk steps of g' = dA*g + x with g0=0,
// store the 16 complex end states. lane = d (coalesced x loads).
// ---------------------------------------------------------------------------
__global__ __launch_bounds__(64) void s4_chunk_state(
    const float* __restrict__ X, const float* __restrict__ log_dt,
    const float* __restrict__ A_real_log, const float* __restrict__ A_imag,
    float* __restrict__ GE)
{
  const int lane = threadIdx.x;
  const int blk = blockIdx.x;
  const int dblk = blk & 15;              // D/64 = 16
  const int c = (blk >> 4) & (kNC - 1);   // NC = 32
  const int b = blk >> 9;
  const int d = dblk * 64 + lane;

  const float delta = s4_delta(log_dt[d]);

  float are[kN], aimv[kN];
  const float4* arl4 = reinterpret_cast<const float4*>(A_real_log + (size_t)d * kN);
  const float4* ai4  = reinterpret_cast<const float4*>(A_imag + (size_t)d * kN);
  #pragma unroll
  for (int q = 0; q < 4; ++q) {
    float4 a = arl4[q];
    float4 im = ai4[q];
    float v[4] = {a.x, a.y, a.z, a.w};
    float w[4] = {im.x, im.y, im.z, im.w};
    #pragma unroll
    for (int j = 0; j < 4; ++j) {
      const int n = q * 4 + j;
      float mag = expf(-delta * expf(v[j]));
      float ph = delta * w[j];
      are[n] = mag * cosf(ph);
      aimv[n] = mag * sinf(ph);
    }
  }

  float gre[kN], gim[kN];
  #pragma unroll
  for (int n = 0; n < kN; ++n) { gre[n] = 0.f; gim[n] = 0.f; }

  const float* xp = X + ((size_t)b * kL + (size_t)c * kChunk) * kD + d;

  float xbuf[kPF];
  #pragma unroll
  for (int i = 0; i < kPF; ++i) xbuf[i] = xp[(size_t)i * kD];

  // main loop: prefetch kPF ahead; epilogue without prefetch
  for (int tt = 0; tt < kChunk - kPF; tt += kPF) {
    #pragma unroll
    for (int j = 0; j < kPF; ++j) {
      const float x = xbuf[j];
      xbuf[j] = xp[(size_t)(tt + j + kPF) * kD];
      #pragma unroll
      for (int n = 0; n < kN; ++n) {
        float tre = fmaf(are[n], gre[n], x);   // x is real: only re gets it
        float tim = are[n] * gim[n];
        float nre = fmaf(-aimv[n], gim[n], tre);
        float nim = fmaf(aimv[n], gre[n], tim);
        gre[n] = nre;
        gim[n] = nim;
      }
    }
  }
  #pragma unroll
  for (int j = 0; j < kPF; ++j) {
    const float x = xbuf[j];
    #pragma unroll
    for (int n = 0; n < kN; ++n) {
      float tre = fmaf(are[n], gre[n], x);
      float tim = are[n] * gim[n];
      float nre = fmaf(-aimv[n], gim[n], tre);
      float nim = fmaf(aimv[n], gre[n], tim);
      gre[n] = nre;
      gim[n] = nim;
    }
  }

  float* gp = GE + ((size_t)(b * kNC + c) * kN * 2) * kD + d;
  #pragma unroll
  for (int n = 0; n < kN; ++n) {
    gp[(size_t)(2 * n) * kD] = gre[n];
    gp[(size_t)(2 * n + 1) * kD] = gim[n];
  }
}

// ---------------------------------------------------------------------------
// K2: per (b, n, d) thread — sequential scan over the NC chunks:
//   carry[c] = s_c,  s_{c+1} = dA^kChunk * s_c + end[c],  s_0 = 0
// dA^kChunk computed directly as exp(kChunk*delta*A).
// ---------------------------------------------------------------------------
__global__ __launch_bounds__(256) void s4_carry(
    const float* __restrict__ GE, const float* __restrict__ log_dt,
    const float* __restrict__ A_real_log, const float* __restrict__ A_imag,
    float* __restrict__ CA)
{
  const int tid = blockIdx.x * 256 + threadIdx.x;  // 0 .. B*N*D-1
  const int d = tid & (kD - 1);
  const int bn = tid >> 10;
  const int n = bn & (kN - 1);
  const int b = bn >> 4;

  const float delta = s4_delta(log_dt[d]);
  const float arl = A_real_log[(size_t)d * kN + n];
  const float aim = A_imag[(size_t)d * kN + n];
  const float LT = delta * (float)kChunk;
  const float mag = expf(-LT * expf(arl));
  const float ph = LT * aim;
  const float aTre = mag * cosf(ph);
  const float aTim = mag * sinf(ph);

  float sre = 0.f, sim = 0.f;
  #pragma unroll 8
  for (int c = 0; c < kNC; ++c) {
    const size_t idx = ((size_t)((b * kNC + c) * kN + n) * 2) * kD + d;
    const float ere = GE[idx];
    const float eim = GE[idx + kD];
    CA[idx] = sre;
    CA[idx + kD] = sim;
    const float nre = fmaf(aTre, sre, fmaf(-aTim, sim, ere));
    const float nim = fmaf(aTre, sim, fmaf(aTim, sre, eim));
    sre = nre;
    sim = nim;
  }
}

// ---------------------------------------------------------------------------
// K3: per (b, chunk, d) thread — re-scan the chunk starting from the carry,
// emit y_t = x*D + sum_n 2*Re(C*dB * g) each step. Coalesced stores.
// ---------------------------------------------------------------------------
__global__ __launch_bounds__(64) void s4_chunk_out(
    const float* __restrict__ X, const float* __restrict__ log_dt,
    const float* __restrict__ A_real_log, const float* __restrict__ A_imag,
    const float* __restrict__ B_re, const float* __restrict__ B_im,
    const float* __restrict__ C_re, const float* __restrict__ C_im,
    const float* __restrict__ Dparam, const float* __restrict__ CA,
    float* __restrict__ Y)
{
  const int lane = threadIdx.x;
  const int blk = blockIdx.x;
  const int dblk = blk & 15;
  const int c = (blk >> 4) & (kNC - 1);
  const int b = blk >> 9;
  const int d = dblk * 64 + lane;

  const float delta = s4_delta(log_dt[d]);

  float are[kN], aimv[kN], cbre[kN], cbim[kN];
  {
    const float4* arl4 = reinterpret_cast<const float4*>(A_real_log + (size_t)d * kN);
    const float4* ai4  = reinterpret_cast<const float4*>(A_imag + (size_t)d * kN);
    const float4* br4  = reinterpret_cast<const float4*>(B_re + (size_t)d * kN);
    const float4* bi4  = reinterpret_cast<const float4*>(B_im + (size_t)d * kN);
    const float4* cr4  = reinterpret_cast<const float4*>(C_re + (size_t)d * kN);
    const float4* ci4  = reinterpret_cast<const float4*>(C_im + (size_t)d * kN);
    #pragma unroll
    for (int q = 0; q < 4; ++q) {
      float4 a = arl4[q];
      float4 im = ai4[q];
      float4 br = br4[q];
      float4 bi = bi4[q];
      float4 cr = cr4[q];
      float4 ci = ci4[q];
      float av[4] = {a.x, a.y, a.z, a.w};
      float iv[4] = {im.x, im.y, im.z, im.w};
      float brv[4] = {br.x, br.y, br.z, br.w};
      float biv[4] = {bi.x, bi.y, bi.z, bi.w};
      float crv[4] = {cr.x, cr.y, cr.z, cr.w};
      float civ[4] = {ci.x, ci.y, ci.z, ci.w};
      #pragma unroll
      for (int j = 0; j < 4; ++j) {
        const int n = q * 4 + j;
        float mag = expf(-delta * expf(av[j]));
        float ph = delta * iv[j];
        are[n] = mag * cosf(ph);
        aimv[n] = mag * sinf(ph);
        float dbre = delta * brv[j];
        float dbim = delta * biv[j];
        cbre[n] = 2.f * (crv[j] * dbre - civ[j] * dbim);   // 2*Re/Im of C*dB
        cbim[n] = 2.f * (crv[j] * dbim + civ[j] * dbre);
      }
    }
  }
  const float Dd = Dparam[d];

  // init g from carries
  float gre[kN], gim[kN];
  const float* cp = CA + ((size_t)(b * kNC + c) * kN * 2) * kD + d;
  #pragma unroll
  for (int n = 0; n < kN; ++n) {
    gre[n] = cp[(size_t)(2 * n) * kD];
    gim[n] = cp[(size_t)(2 * n + 1) * kD];
  }

  const size_t base = ((size_t)b * kL + (size_t)c * kChunk) * kD + d;
  const float* xp = X + base;
  float* yp = Y + base;

  float xbuf[kPF];
  #pragma unroll
  for (int i = 0; i < kPF; ++i) xbuf[i] = xp[(size_t)i * kD];

  for (int tt = 0; tt < kChunk - kPF; tt += kPF) {
    #pragma unroll
    for (int j = 0; j < kPF; ++j) {
      const int t = tt + j;
      const float x = xbuf[j];
      xbuf[j] = xp[(size_t)(t + kPF) * kD];
      float ya0 = x * Dd;
      float ya1 = 0.f, ya2 = 0.f, ya3 = 0.f;
      #pragma unroll
      for (int n = 0; n < kN; ++n) {
        float tre = fmaf(are[n], gre[n], x);
        float tim = are[n] * gim[n];
        float nre = fmaf(-aimv[n], gim[n], tre);
        float nim = fmaf(aimv[n], gre[n], tim);
        gre[n] = nre;
        gim[n] = nim;
        if ((n & 3) == 0) { ya0 = fmaf(cbre[n], nre, ya0); ya0 = fmaf(-cbim[n], nim, ya0); }
        else if ((n & 3) == 1) { ya1 = fmaf(cbre[n], nre, ya1); ya1 = fmaf(-cbim[n], nim, ya1); }
        else if ((n & 3) == 2) { ya2 = fmaf(cbre[n], nre, ya2); ya2 = fmaf(-cbim[n], nim, ya2); }
        else { ya3 = fmaf(cbre[n], nre, ya3); ya3 = fmaf(-cbim[n], nim, ya3); }
      }
      yp[(size_t)t * kD] = (ya0 + ya1) + (ya2 + ya3);
    }
  }
  {
    const int tt = kChunk - kPF;
    #pragma unroll
    for (int j = 0; j < kPF; ++j) {
      const int t = tt + j;
      const float x = xbuf[j];
      float ya0 = x * Dd;
      float ya1 = 0.f, ya2 = 0.f, ya3 = 0.f;
      #pragma unroll
      for (int n = 0; n < kN; ++n) {
        float tre = fmaf(are[n], gre[n], x);
        float tim = are[n] * gim[n];
        float nre = fmaf(-aimv[n], gim[n], tre);
        float nim = fmaf(aimv[n], gre[n], tim);
        gre[n] = nre;
        gim[n] = nim;
        if ((n & 3) == 0) { ya0 = fmaf(cbre[n], nre, ya0); ya0 = fmaf(-cbim[n], nim, ya0); }
        else if ((n & 3) == 1) { ya1 = fmaf(cbre[n], nre, ya1); ya1 = fmaf(-cbim[n], nim, ya1); }
        else if ((n & 3) == 2) { ya2 = fmaf(cbre[n], nre, ya2); ya2 = fmaf(-cbim[n], nim, ya2); }
        else { ya3 = fmaf(cbre[n], nre, ya3); ya3 = fmaf(-cbim[n], nim, ya3); }
      }
      yp[(size_t)t * kD] = (ya0 + ya1) + (ya2 + ya3);
    }
  }
}

extern "C" void kernel_launch(void* const* d_in, const int* in_sizes, int n_in,
                              void* d_out, int out_size, void* d_ws, size_t ws_size,
                              hipStream_t stream) {
  const float* X          = (const float*)d_in[0];
  const float* log_dt     = (const float*)d_in[1];
  const float* A_real_log = (const float*)d_in[2];
  const float* A_imag     = (const float*)d_in[3];
  const float* B_re       = (const float*)d_in[4];
  const float* B_im       = (const float*)d_in[5];
  const float* C_re       = (const float*)d_in[6];
  const float* C_im       = (const float*)d_in[7];
  const float* Dparam     = (const float*)d_in[8];
  float* Y = (float*)d_out;

  // Chunk end-states (B*NC*N*2*D = 2.1M floats = 8.4 MB) live in d_out;
  // K3 never reads GE (only CA) and overwrites the region with y.
  float* GE = Y;
  // Carries (8.4 MB) in workspace.
  float* CA = (float*)d_ws;

  const int nblk = kB * kNC * (kD / 64);  // 1024
  s4_chunk_state<<<nblk, 64, 0, stream>>>(X, log_dt, A_real_log, A_imag, GE);
  s4_carry<<<(kB * kN * kD) / 256, 256, 0, stream>>>(GE, log_dt, A_real_log, A_imag, CA);
  s4_chunk_out<<<nblk, 64, 0, stream>>>(X, log_dt, A_real_log, A_imag,
                                        B_re, B_im, C_re, C_im, Dparam, CA, Y);
}